// Round 1
// baseline (71.798 us; speedup 1.0000x reference)
//
#include <hip/hip_runtime.h>
#include <hip/hip_bf16.h>

#define MM 512
#define LL 31
#define LDB 15
#define NPIX (MM*MM)
#define NOUT (NPIX*LDB)

// ---- compile-time resize weight table (jax.image.resize linear, antialias) ----
struct WTab { float w[LDB][5]; int i0[LDB]; };

constexpr WTab make_wtab() {
    WTab t{};
    const double inv_scale = 31.0 / 15.0;   // 1/scale
    const double ks = inv_scale;            // kernel_scale = max(inv_scale, 1)
    for (int k = 0; k < LDB; ++k) {
        double sf = (k + 0.5) * inv_scale - 0.5;
        double wv[LL] = {};
        double wsum = 0.0;
        for (int i = 0; i < LL; ++i) {
            double d = sf - (double)i;
            if (d < 0) d = -d;
            double w = 1.0 - d / ks;
            if (w < 0) w = 0;
            wv[i] = w;
            wsum += w;
        }
        int first = 0;
        while (first < LL && wv[first] == 0.0) ++first;
        t.i0[k] = first;
        for (int j = 0; j < 5; ++j) {
            int i = first + j;
            t.w[k][j] = (i < LL) ? (float)(wv[i] / wsum) : 0.0f;
        }
    }
    return t;
}

__constant__ WTab c_wtab = make_wtab();

__device__ __forceinline__ unsigned int enc_f32(float f) {
    unsigned int b = __float_as_uint(f);
    return (b & 0x80000000u) ? ~b : (b | 0x80000000u);
}
__device__ __forceinline__ float dec_f32(unsigned int u) {
    unsigned int b = (u & 0x80000000u) ? (u & 0x7fffffffu) : ~u;
    return __uint_as_float(b);
}

// ---- pass 1: r = sum_k H*Xr - y ; global max of H*r via atomic ----
template <bool STORE_XN>
__global__ __launch_bounds__(256) void pass1_k(const float* __restrict__ X,
                                               const float* __restrict__ y,
                                               const float* __restrict__ H,
                                               float* __restrict__ r_or_xn,
                                               unsigned int* __restrict__ gmax) {
    int p = blockIdx.x * blockDim.x + threadIdx.x;
    if (p >= NPIX) return;

    const float* xp = X + (size_t)p * LL;
    float xv[LL];
#pragma unroll
    for (int i = 0; i < LL; ++i) xv[i] = xp[i];

    float xr[LDB];
#pragma unroll
    for (int k = 0; k < LDB; ++k) {
        int i0 = c_wtab.i0[k];
        float s = 0.f;
#pragma unroll
        for (int j = 0; j < 5; ++j) {
            int i = i0 + j;
            if (i > LL - 1) i = LL - 1;   // weight is 0 there; clamp keeps load in-bounds
            s += c_wtab.w[k][j] * xv[i];
        }
        xr[k] = s;
    }

    const float* hp = H + (size_t)p * LDB;
    float hv[LDB];
    float s = 0.f, hmin = 1e30f, hmax = -1e30f;
#pragma unroll
    for (int k = 0; k < LDB; ++k) {
        float h = hp[k];
        hv[k] = h;
        s += h * xr[k];
        hmin = fminf(hmin, h);
        hmax = fmaxf(hmax, h);
    }
    float r = s - y[p];

    if (STORE_XN) {
        float* op = r_or_xn + (size_t)p * LDB;
#pragma unroll
        for (int k = 0; k < LDB; ++k) op[k] = hv[k] * r;
    } else {
        r_or_xn[p] = r;
    }

    // per-pixel max of H*r over k, H >= 0
    float m = (r > 0.f) ? r * hmax : r * hmin;
    // wave64 butterfly max
#pragma unroll
    for (int off = 32; off; off >>= 1) m = fmaxf(m, __shfl_xor(m, off));
    if ((threadIdx.x & 63) == 0) {
        atomicMax(gmax, enc_f32(m));
    }
}

// ---- pass 2 (fast path): out = H * r / max ----
__global__ __launch_bounds__(256) void pass2_k(const float* __restrict__ H,
                                               const float* __restrict__ r_in,
                                               const unsigned int* __restrict__ gmax,
                                               float* __restrict__ out) {
    float inv = 1.0f / dec_f32(*gmax);
    int idx = blockIdx.x * blockDim.x + threadIdx.x;
    if (idx >= NOUT) return;
    int p = idx / LDB;
    out[idx] = H[idx] * r_in[p] * inv;
}

// ---- pass 2 (fallback): out *= 1/max in place ----
__global__ __launch_bounds__(256) void pass2_inplace_k(float* __restrict__ out,
                                                       const unsigned int* __restrict__ gmax) {
    float inv = 1.0f / dec_f32(*gmax);
    int idx = blockIdx.x * blockDim.x + threadIdx.x;
    if (idx >= NOUT) return;
    out[idx] *= inv;
}

extern "C" void kernel_launch(void* const* d_in, const int* in_sizes, int n_in,
                              void* d_out, int out_size, void* d_ws, size_t ws_size,
                              hipStream_t stream) {
    const float* X = (const float*)d_in[0];
    const float* y = (const float*)d_in[1];
    const float* H = (const float*)d_in[2];
    float* out = (float*)d_out;

    unsigned int* gmax = (unsigned int*)d_ws;
    float* r_buf = (float*)((char*)d_ws + 256);

    // gmax slot must be re-initialized every call (ws is not re-poisoned)
    hipMemsetAsync(d_ws, 0, 256, stream);  // 0 encodes below every real float

    const int blk = 256;
    const int g1 = (NPIX + blk - 1) / blk;      // 1024
    const int g2 = (NOUT + blk - 1) / blk;      // 15360

    if (ws_size >= 256 + (size_t)NPIX * sizeof(float)) {
        pass1_k<false><<<g1, blk, 0, stream>>>(X, y, H, r_buf, gmax);
        pass2_k<<<g2, blk, 0, stream>>>(H, r_buf, gmax, out);
    } else {
        pass1_k<true><<<g1, blk, 0, stream>>>(X, y, H, out, gmax);
        pass2_inplace_k<<<g2, blk, 0, stream>>>(out, gmax);
    }
}

// Round 2
// 71.228 us; speedup vs baseline: 1.0080x; 1.0080x over previous
//
#include <hip/hip_runtime.h>
#include <hip/hip_bf16.h>

#define MM 512
#define LL 31
#define LDB 15
#define NPIX (MM*MM)
#define NOUT (NPIX*LDB)

// ---- compile-time resize weight table (jax.image.resize linear, antialias) ----
struct WTab { float w[LDB][5]; int i0[LDB]; };

constexpr WTab make_wtab() {
    WTab t{};
    const double inv_scale = 31.0 / 15.0;
    const double ks = inv_scale;
    for (int k = 0; k < LDB; ++k) {
        double sf = (k + 0.5) * inv_scale - 0.5;
        double wv[LL] = {};
        double wsum = 0.0;
        for (int i = 0; i < LL; ++i) {
            double d = sf - (double)i;
            if (d < 0) d = -d;
            double w = 1.0 - d / ks;
            if (w < 0) w = 0;
            wv[i] = w;
            wsum += w;
        }
        int first = 0;
        while (first < LL && wv[first] == 0.0) ++first;
        t.i0[k] = first;
        for (int j = 0; j < 5; ++j) {
            int i = first + j;
            t.w[k][j] = (i < LL) ? (float)(wv[i] / wsum) : 0.0f;
        }
    }
    return t;
}

__constant__ WTab c_wtab = make_wtab();

__device__ __forceinline__ unsigned int enc_f32(float f) {
    unsigned int b = __float_as_uint(f);
    return (b & 0x80000000u) ? ~b : (b | 0x80000000u);
}
__device__ __forceinline__ float dec_f32(unsigned int u) {
    unsigned int b = (u & 0x80000000u) ? (u & 0x7fffffffu) : ~u;
    return __uint_as_float(b);
}

// LDS tile: max(256*31, 256*15) floats = 7936 floats = 31.75 KB
#define XTILE_F  (256*LL)            // 7936 floats
#define XTILE_V4 (XTILE_F/4)         // 1984 float4
#define HTILE_F  (256*LDB)           // 3840 floats
#define HTILE_V4 (HTILE_F/4)         // 960 float4

// ---- pass 1: r = sum_k H*Xr - y ; global max of H*r via atomic ----
template <bool STORE_XN>
__global__ __launch_bounds__(256) void pass1_k(const float* __restrict__ X,
                                               const float* __restrict__ y,
                                               const float* __restrict__ H,
                                               float* __restrict__ r_or_xn,
                                               unsigned int* __restrict__ gmax) {
    __shared__ float lds[XTILE_F];
    float4* lds4 = (float4*)lds;

    const int tid = threadIdx.x;
    const int p   = blockIdx.x * 256 + tid;   // grid is exact: 1024 * 256 = NPIX

    // ---- stage X tile (256 px * 31 bands), coalesced float4 ----
    {
        const float4* X4 = (const float4*)(X + (size_t)blockIdx.x * XTILE_F);
#pragma unroll
        for (int j = 0; j < 7; ++j)
            lds4[j * 256 + tid] = X4[j * 256 + tid];
        if (tid < XTILE_V4 - 7 * 256)                    // 1984 - 1792 = 192
            lds4[7 * 256 + tid] = X4[7 * 256 + tid];
    }
    __syncthreads();

    // ---- per-pixel spectral resize from LDS ----
    float xv[LL];
#pragma unroll
    for (int i = 0; i < LL; ++i) xv[i] = lds[tid * LL + i];

    float xr[LDB];
#pragma unroll
    for (int k = 0; k < LDB; ++k) {
        int i0 = c_wtab.i0[k];
        float s = 0.f;
#pragma unroll
        for (int j = 0; j < 5; ++j) {
            int i = i0 + j;
            if (i > LL - 1) i = LL - 1;   // weight 0 there; clamp keeps index in-bounds
            s += c_wtab.w[k][j] * xv[i];
        }
        xr[k] = s;
    }
    __syncthreads();   // all X reads done before overwriting LDS with H

    // ---- stage H tile (256 px * 15 bands), coalesced float4 ----
    {
        const float4* H4 = (const float4*)(H + (size_t)blockIdx.x * HTILE_F);
#pragma unroll
        for (int j = 0; j < 3; ++j)
            lds4[j * 256 + tid] = H4[j * 256 + tid];
        if (tid < HTILE_V4 - 3 * 256)                    // 960 - 768 = 192
            lds4[3 * 256 + tid] = H4[3 * 256 + tid];
    }
    __syncthreads();

    float s = 0.f, hmin = 1e30f, hmax = -1e30f;
#pragma unroll
    for (int k = 0; k < LDB; ++k) {
        float h = lds[tid * LDB + k];
        s += h * xr[k];
        hmin = fminf(hmin, h);
        hmax = fmaxf(hmax, h);
    }
    float r = s - y[p];

    if (STORE_XN) {
        float* op = r_or_xn + (size_t)p * LDB;
#pragma unroll
        for (int k = 0; k < LDB; ++k) op[k] = lds[tid * LDB + k] * r;
    } else {
        r_or_xn[p] = r;
    }

    // per-pixel max of H*r over k (H >= 0): r>0 ? r*hmax : r*hmin
    float m = (r > 0.f) ? r * hmax : r * hmin;
#pragma unroll
    for (int off = 32; off; off >>= 1) m = fmaxf(m, __shfl_xor(m, off));
    if ((tid & 63) == 0) atomicMax(gmax, enc_f32(m));
}

// ---- pass 2 (fast path): out = H * r / max, float4-vectorized ----
__global__ __launch_bounds__(256) void pass2_k(const float4* __restrict__ H4,
                                               const float* __restrict__ r_in,
                                               const unsigned int* __restrict__ gmax,
                                               float4* __restrict__ out4) {
    float inv = 1.0f / dec_f32(*gmax);
    int i4 = blockIdx.x * 256 + threadIdx.x;   // grid exact: 3840 * 256 = NOUT/4
    int i0 = i4 * 4;

    float4 h = H4[i4];

    int p0 = i0 / LDB;                 // magic-mul, cheap
    int rm = i0 - p0 * LDB;
    int p1 = p0 + 1; if (p1 > NPIX - 1) p1 = NPIX - 1;
    float rv0 = r_in[p0] * inv;
    float rv1 = r_in[p1] * inv;

    float4 o;
    o.x = h.x * ((rm + 0 < LDB) ? rv0 : rv1);
    o.y = h.y * ((rm + 1 < LDB) ? rv0 : rv1);
    o.z = h.z * ((rm + 2 < LDB) ? rv0 : rv1);
    o.w = h.w * ((rm + 3 < LDB) ? rv0 : rv1);
    out4[i4] = o;
}

// ---- pass 2 (fallback): out *= 1/max in place ----
__global__ __launch_bounds__(256) void pass2_inplace_k(float* __restrict__ out,
                                                       const unsigned int* __restrict__ gmax) {
    float inv = 1.0f / dec_f32(*gmax);
    int idx = blockIdx.x * blockDim.x + threadIdx.x;
    if (idx >= NOUT) return;
    out[idx] *= inv;
}

extern "C" void kernel_launch(void* const* d_in, const int* in_sizes, int n_in,
                              void* d_out, int out_size, void* d_ws, size_t ws_size,
                              hipStream_t stream) {
    const float* X = (const float*)d_in[0];
    const float* y = (const float*)d_in[1];
    const float* H = (const float*)d_in[2];
    float* out = (float*)d_out;

    unsigned int* gmax = (unsigned int*)d_ws;
    float* r_buf = (float*)((char*)d_ws + 256);

    // gmax must be re-initialized every call (ws is not re-poisoned between replays)
    hipMemsetAsync(d_ws, 0, 256, stream);  // 0 encodes below every real float

    const int blk = 256;
    const int g1 = NPIX / blk;          // 1024
    const int g2v = (NOUT / 4) / blk;   // 3840
    const int g2s = (NOUT + blk - 1) / blk;

    if (ws_size >= 256 + (size_t)NPIX * sizeof(float)) {
        pass1_k<false><<<g1, blk, 0, stream>>>(X, y, H, r_buf, gmax);
        pass2_k<<<g2v, blk, 0, stream>>>((const float4*)H, r_buf, gmax, (float4*)out);
    } else {
        pass1_k<true><<<g1, blk, 0, stream>>>(X, y, H, out, gmax);
        pass2_inplace_k<<<g2s, blk, 0, stream>>>(out, gmax);
    }
}

// Round 3
// 23.675 us; speedup vs baseline: 3.0326x; 3.0085x over previous
//
#include <hip/hip_runtime.h>
#include <hip/hip_bf16.h>

#define MM 512
#define LL 31
#define LDB 15
#define NPIX (MM*MM)
#define NOUT (NPIX*LDB)
#define NBLK1 (NPIX/256)   // 1024 pass1 blocks

// ---- compile-time resize weight table (jax.image.resize linear, antialias) ----
struct WTab { float w[LDB][5]; int i0[LDB]; };

constexpr WTab make_wtab() {
    WTab t{};
    const double inv_scale = 31.0 / 15.0;
    const double ks = inv_scale;
    for (int k = 0; k < LDB; ++k) {
        double sf = (k + 0.5) * inv_scale - 0.5;
        double wv[LL] = {};
        double wsum = 0.0;
        for (int i = 0; i < LL; ++i) {
            double d = sf - (double)i;
            if (d < 0) d = -d;
            double w = 1.0 - d / ks;
            if (w < 0) w = 0;
            wv[i] = w;
            wsum += w;
        }
        int first = 0;
        while (first < LL && wv[first] == 0.0) ++first;
        t.i0[k] = first;
        for (int j = 0; j < 5; ++j) {
            int i = first + j;
            t.w[k][j] = (i < LL) ? (float)(wv[i] / wsum) : 0.0f;
        }
    }
    return t;
}

__constant__ WTab c_wtab = make_wtab();

__device__ __forceinline__ unsigned int enc_f32(float f) {
    unsigned int b = __float_as_uint(f);
    return (b & 0x80000000u) ? ~b : (b | 0x80000000u);
}
__device__ __forceinline__ float dec_f32(unsigned int u) {
    unsigned int b = (u & 0x80000000u) ? (u & 0x7fffffffu) : ~u;
    return __uint_as_float(b);
}

#define XTILE_F  (256*LL)            // 7936 floats = 31.75 KB
#define XTILE_V4 (XTILE_F/4)         // 1984
#define HTILE_F  (256*LDB)           // 3840 floats
#define HTILE_V4 (HTILE_F/4)         // 960

// ---- pass 1: r = sum_k H*Xr - y ; per-block max of H*r (NO global atomics) ----
template <bool ATOMIC_FALLBACK>
__global__ __launch_bounds__(256) void pass1_k(const float* __restrict__ X,
                                               const float* __restrict__ y,
                                               const float* __restrict__ H,
                                               float* __restrict__ r_or_xn,
                                               float* __restrict__ partials,
                                               unsigned int* __restrict__ gmax_atomic) {
    __shared__ float lds[XTILE_F];
    __shared__ float redbuf[4];
    float4* lds4 = (float4*)lds;

    const int tid = threadIdx.x;
    const int p   = blockIdx.x * 256 + tid;   // grid exact: 1024*256 = NPIX

    // ---- stage X tile (256 px * 31 bands), coalesced float4 ----
    {
        const float4* X4 = (const float4*)(X + (size_t)blockIdx.x * XTILE_F);
#pragma unroll
        for (int j = 0; j < 7; ++j)
            lds4[j * 256 + tid] = X4[j * 256 + tid];
        if (tid < XTILE_V4 - 7 * 256)
            lds4[7 * 256 + tid] = X4[7 * 256 + tid];
    }
    __syncthreads();

    float xv[LL];
#pragma unroll
    for (int i = 0; i < LL; ++i) xv[i] = lds[tid * LL + i];

    float xr[LDB];
#pragma unroll
    for (int k = 0; k < LDB; ++k) {
        int i0 = c_wtab.i0[k];
        float s = 0.f;
#pragma unroll
        for (int j = 0; j < 5; ++j) {
            int i = i0 + j;
            if (i > LL - 1) i = LL - 1;   // weight 0 there; clamp keeps index in-bounds
            s += c_wtab.w[k][j] * xv[i];
        }
        xr[k] = s;
    }
    __syncthreads();   // X reads done before overwriting with H

    // ---- stage H tile ----
    {
        const float4* H4 = (const float4*)(H + (size_t)blockIdx.x * HTILE_F);
#pragma unroll
        for (int j = 0; j < 3; ++j)
            lds4[j * 256 + tid] = H4[j * 256 + tid];
        if (tid < HTILE_V4 - 3 * 256)
            lds4[3 * 256 + tid] = H4[3 * 256 + tid];
    }
    __syncthreads();

    float s = 0.f, hmin = 1e30f, hmax = -1e30f;
#pragma unroll
    for (int k = 0; k < LDB; ++k) {
        float h = lds[tid * LDB + k];
        s += h * xr[k];
        hmin = fminf(hmin, h);
        hmax = fmaxf(hmax, h);
    }
    float r = s - y[p];

    if (ATOMIC_FALLBACK) {
        float* op = r_or_xn + (size_t)p * LDB;
#pragma unroll
        for (int k = 0; k < LDB; ++k) op[k] = lds[tid * LDB + k] * r;
    } else {
        r_or_xn[p] = r;
    }

    // per-pixel max of H*r over k (H >= 0): r>0 ? r*hmax : r*hmin
    float m = (r > 0.f) ? r * hmax : r * hmin;
#pragma unroll
    for (int off = 32; off; off >>= 1) m = fmaxf(m, __shfl_xor(m, off));

    if (ATOMIC_FALLBACK) {
        if ((tid & 63) == 0) atomicMax(gmax_atomic, enc_f32(m));
    } else {
        if ((tid & 63) == 0) redbuf[tid >> 6] = m;
        __syncthreads();
        if (tid == 0)
            partials[blockIdx.x] =
                fmaxf(fmaxf(redbuf[0], redbuf[1]), fmaxf(redbuf[2], redbuf[3]));
    }
}

// ---- reduce 1024 partials -> gmax (single block) ----
__global__ __launch_bounds__(256) void reduce_k(const float* __restrict__ partials,
                                                float* __restrict__ gmaxf) {
    __shared__ float rb[4];
    int tid = threadIdx.x;
    float m = -1e30f;
#pragma unroll
    for (int j = 0; j < NBLK1 / 256; ++j)
        m = fmaxf(m, partials[j * 256 + tid]);
#pragma unroll
    for (int off = 32; off; off >>= 1) m = fmaxf(m, __shfl_xor(m, off));
    if ((tid & 63) == 0) rb[tid >> 6] = m;
    __syncthreads();
    if (tid == 0)
        gmaxf[0] = fmaxf(fmaxf(rb[0], rb[1]), fmaxf(rb[2], rb[3]));
}

// ---- pass 2 (fast path): out = H * r / max, float4-vectorized ----
__global__ __launch_bounds__(256) void pass2_k(const float4* __restrict__ H4,
                                               const float* __restrict__ r_in,
                                               const float* __restrict__ gmaxf,
                                               float4* __restrict__ out4) {
    float inv = 1.0f / gmaxf[0];
    int i4 = blockIdx.x * 256 + threadIdx.x;   // grid exact: 3840*256 = NOUT/4
    int i0 = i4 * 4;

    float4 h = H4[i4];

    int p0 = i0 / LDB;
    int rm = i0 - p0 * LDB;
    int p1 = p0 + 1; if (p1 > NPIX - 1) p1 = NPIX - 1;
    float rv0 = r_in[p0] * inv;
    float rv1 = r_in[p1] * inv;

    float4 o;
    o.x = h.x * ((rm + 0 < LDB) ? rv0 : rv1);
    o.y = h.y * ((rm + 1 < LDB) ? rv0 : rv1);
    o.z = h.z * ((rm + 2 < LDB) ? rv0 : rv1);
    o.w = h.w * ((rm + 3 < LDB) ? rv0 : rv1);
    out4[i4] = o;
}

// ---- pass 2 (fallback): out *= 1/max in place ----
__global__ __launch_bounds__(256) void pass2_inplace_k(float* __restrict__ out,
                                                       const unsigned int* __restrict__ gmax) {
    float inv = 1.0f / dec_f32(*gmax);
    int idx = blockIdx.x * blockDim.x + threadIdx.x;
    if (idx >= NOUT) return;
    out[idx] *= inv;
}

extern "C" void kernel_launch(void* const* d_in, const int* in_sizes, int n_in,
                              void* d_out, int out_size, void* d_ws, size_t ws_size,
                              hipStream_t stream) {
    const float* X = (const float*)d_in[0];
    const float* y = (const float*)d_in[1];
    const float* H = (const float*)d_in[2];
    float* out = (float*)d_out;

    // ws layout: [0,256)=gmax  [256,256+4K)=partials  [256+4K, ...)=r_buf
    unsigned int* gmax_u = (unsigned int*)d_ws;
    float* gmax_f  = (float*)d_ws;
    float* partials = (float*)((char*)d_ws + 256);
    float* r_buf    = (float*)((char*)d_ws + 256 + NBLK1 * sizeof(float));

    const int blk = 256;
    const int g1  = NBLK1;              // 1024
    const int g2v = (NOUT / 4) / blk;   // 3840
    const int g2s = (NOUT + blk - 1) / blk;

    size_t need = 256 + (size_t)NBLK1 * 4 + (size_t)NPIX * 4;
    if (ws_size >= need) {
        pass1_k<false><<<g1, blk, 0, stream>>>(X, y, H, r_buf, partials, gmax_u);
        reduce_k<<<1, blk, 0, stream>>>(partials, gmax_f);
        pass2_k<<<g2v, blk, 0, stream>>>((const float4*)H, r_buf, gmax_f, (float4*)out);
    } else {
        hipMemsetAsync(d_ws, 0, 256, stream);  // encoded -inf floor for atomic path
        pass1_k<true><<<g1, blk, 0, stream>>>(X, y, H, out, partials, gmax_u);
        pass2_inplace_k<<<g2s, blk, 0, stream>>>(out, gmax_u);
    }
}